// Round 6
// baseline (303.469 us; speedup 1.0000x reference)
//
#include <hip/hip_runtime.h>
#include <math.h>

#define N_NODES 10000
#define N_EDGES 640000
#define DIM     128
#define NCLS    10
#define NGRAPH  64
#define CSTRIDE 256   // padded adjacency stride; in-degree ~Poisson(64), max ~110 << 256

typedef unsigned int uint32;
typedef unsigned short ushort16;

__device__ __forceinline__ ushort16 f32_to_bf16_rne(float f) {
    uint32 u = __float_as_uint(f);
    u = (u + 0x7fffu + ((u >> 16) & 1u)) >> 16;   // round-to-nearest-even
    return (ushort16)u;
}

// ---------------- fused adjacency build + layer-1 GEMM ----------------
// Blocks 0..624: g1 = bf16(x @ W1) (unscaled; runs concurrent with build).
// Blocks 640..3199: XCD-phased edge scatter. Phase p (= blockIdx%8, the XCD
// round-robin heuristic) handles only edges with dst%8==p, so every col cache
// line is dirtied by a single XCD's L2 and written back once (kills the 34MB
// partial-line write amplification seen in R5). dst[] is scanned 8x (cheap).
__global__ __launch_bounds__(256) void build_gemm1(const int* __restrict__ src,
                                                   const int* __restrict__ dst,
                                                   int* __restrict__ deg,
                                                   ushort16* __restrict__ col,
                                                   const float* __restrict__ X,
                                                   const float* __restrict__ W,
                                                   ushort16* __restrict__ Gh) {
    if (blockIdx.x < 625) {
        int c    = threadIdx.x & 127;
        int rg   = threadIdx.x >> 7;
        int row0 = blockIdx.x * 16 + rg * 8;
        const float* xb = X + row0 * DIM;
        float acc[8] = {0.f, 0.f, 0.f, 0.f, 0.f, 0.f, 0.f, 0.f};
        for (int k = 0; k < DIM; k += 4) {
            float w0 = W[(k + 0) * DIM + c];
            float w1 = W[(k + 1) * DIM + c];
            float w2 = W[(k + 2) * DIM + c];
            float w3 = W[(k + 3) * DIM + c];
#pragma unroll
            for (int r = 0; r < 8; r++) {
                float4 xv = *(const float4*)(xb + r * DIM + k);
                acc[r] += xv.x * w0 + xv.y * w1 + xv.z * w2 + xv.w * w3;
            }
        }
#pragma unroll
        for (int r = 0; r < 8; r++)
            Gh[(row0 + r) * DIM + c] = f32_to_bf16_rne(acc[r]);
    } else if (blockIdx.x >= 640) {
        int j     = blockIdx.x - 640;   // 0..2559 (640 % 8 == 0)
        int phase = blockIdx.x & 7;     // target XCD
        int group = j >> 3;             // 0..319, partitions the edge array
        int base  = group * 2048;
#pragma unroll
        for (int it = 0; it < 8; it++) {
            int e = base + it * 256 + (int)threadIdx.x;
            if (e < N_EDGES) {
                int d = dst[e];
                if ((d & 7) == phase) {
                    int r = atomicAdd(&deg[d], 1);
                    if (r < CSTRIDE) col[(d << 8) + r] = (ushort16)src[e];
                }
            }
        }
    }
}

// ---------------- layer-1 aggregation (computes dis on the fly) ----------------
// out[v] = relu( sv * ( sv*g[v] + sum_u s_u*g[u] ) ), s = rsqrt(deg+1).
// Also writes dis[v]=sv for later layers. One wave per node, lane owns 2 feats.
__global__ __launch_bounds__(256) void agg1_kernel(const ushort16* __restrict__ Gh,
                                                   const int* __restrict__ deg,
                                                   const ushort16* __restrict__ col,
                                                   float* __restrict__ dis,
                                                   float* __restrict__ xout) {
    int v    = blockIdx.x * 4 + (threadIdx.x >> 6);
    int lane = threadIdx.x & 63;
    const uint32* g32 = (const uint32*)Gh;
    const ushort16* cv = col + (v << 8);
    int dv = deg[v];
    float sv = rsqrtf((float)dv + 1.0f);
    if (lane == 0) dis[v] = sv;

    uint32 us = g32[(v << 6) + lane];
    float a0 = sv * __uint_as_float(us << 16);
    float a1 = sv * __uint_as_float(us & 0xffff0000u);
    float b0 = 0.f, b1 = 0.f, c0 = 0.f, c1 = 0.f;
    float d0 = 0.f, d1 = 0.f, e0 = 0.f, e1 = 0.f;

    int k = 0;
    for (; k + 8 <= dv; k += 8) {
        uint4 q = *(const uint4*)(cv + k);
        int u0 = q.x & 0xffff, u1 = q.x >> 16;
        int u2 = q.y & 0xffff, u3 = q.y >> 16;
        int u4 = q.z & 0xffff, u5 = q.z >> 16;
        int u6 = q.w & 0xffff, u7 = q.w >> 16;
        uint32 w0 = g32[(u0 << 6) + lane];
        uint32 w1 = g32[(u1 << 6) + lane];
        uint32 w2 = g32[(u2 << 6) + lane];
        uint32 w3 = g32[(u3 << 6) + lane];
        uint32 w4 = g32[(u4 << 6) + lane];
        uint32 w5 = g32[(u5 << 6) + lane];
        uint32 w6 = g32[(u6 << 6) + lane];
        uint32 w7 = g32[(u7 << 6) + lane];
        float s0 = rsqrtf((float)deg[u0] + 1.0f);
        float s1 = rsqrtf((float)deg[u1] + 1.0f);
        float s2 = rsqrtf((float)deg[u2] + 1.0f);
        float s3 = rsqrtf((float)deg[u3] + 1.0f);
        float s4 = rsqrtf((float)deg[u4] + 1.0f);
        float s5 = rsqrtf((float)deg[u5] + 1.0f);
        float s6 = rsqrtf((float)deg[u6] + 1.0f);
        float s7 = rsqrtf((float)deg[u7] + 1.0f);
        a0 += s0 * __uint_as_float(w0 << 16); a1 += s0 * __uint_as_float(w0 & 0xffff0000u);
        b0 += s1 * __uint_as_float(w1 << 16); b1 += s1 * __uint_as_float(w1 & 0xffff0000u);
        c0 += s2 * __uint_as_float(w2 << 16); c1 += s2 * __uint_as_float(w2 & 0xffff0000u);
        d0 += s3 * __uint_as_float(w3 << 16); d1 += s3 * __uint_as_float(w3 & 0xffff0000u);
        a0 += s4 * __uint_as_float(w4 << 16); a1 += s4 * __uint_as_float(w4 & 0xffff0000u);
        b0 += s5 * __uint_as_float(w5 << 16); b1 += s5 * __uint_as_float(w5 & 0xffff0000u);
        c0 += s6 * __uint_as_float(w6 << 16); c1 += s6 * __uint_as_float(w6 & 0xffff0000u);
        d0 += s7 * __uint_as_float(w7 << 16); d1 += s7 * __uint_as_float(w7 & 0xffff0000u);
    }
    for (; k < dv; k++) {
        int u = cv[k];
        uint32 w = g32[(u << 6) + lane];
        float s = rsqrtf((float)deg[u] + 1.0f);
        e0 += s * __uint_as_float(w << 16);
        e1 += s * __uint_as_float(w & 0xffff0000u);
    }
    float r0 = sv * (((a0 + b0) + (c0 + d0)) + e0);
    float r1 = sv * (((a1 + b1) + (c1 + d1)) + e1);
    float2 out;
    out.x = r0 > 0.f ? r0 : 0.f;
    out.y = r1 > 0.f ? r1 : 0.f;
    *(float2*)(xout + v * DIM + lane * 2) = out;
}

// ---------------- layers 2-4 ----------------

// g = bf16( (x @ W) * dis[row] )
__global__ __launch_bounds__(256) void gemm_scale(const float* __restrict__ X,
                                                  const float* __restrict__ W,
                                                  const float* __restrict__ dis,
                                                  ushort16* __restrict__ Gh) {
    int c    = threadIdx.x & 127;
    int rg   = threadIdx.x >> 7;
    int row0 = blockIdx.x * 16 + rg * 8;
    const float* xb = X + row0 * DIM;
    float acc[8] = {0.f, 0.f, 0.f, 0.f, 0.f, 0.f, 0.f, 0.f};
    for (int k = 0; k < DIM; k += 4) {
        float w0 = W[(k + 0) * DIM + c];
        float w1 = W[(k + 1) * DIM + c];
        float w2 = W[(k + 2) * DIM + c];
        float w3 = W[(k + 3) * DIM + c];
#pragma unroll
        for (int r = 0; r < 8; r++) {
            float4 xv = *(const float4*)(xb + r * DIM + k);
            acc[r] += xv.x * w0 + xv.y * w1 + xv.z * w2 + xv.w * w3;
        }
    }
#pragma unroll
    for (int r = 0; r < 8; r++) {
        int row = row0 + r;
        Gh[row * DIM + c] = f32_to_bf16_rne(acc[r] * dis[row]);
    }
}

// x_out[v] = relu( dis[v] * ( g[v] + sum_u g[u] ) )   (g already dis-scaled)
__global__ __launch_bounds__(256) void agg_kernel(const ushort16* __restrict__ Gh,
                                                  const int* __restrict__ deg,
                                                  const ushort16* __restrict__ col,
                                                  const float* __restrict__ dis,
                                                  float* __restrict__ xout) {
    int v    = blockIdx.x * 4 + (threadIdx.x >> 6);
    int lane = threadIdx.x & 63;
    const uint32* g32 = (const uint32*)Gh;
    const ushort16* cv = col + (v << 8);
    int dv = deg[v];

    uint32 us = g32[(v << 6) + lane];
    float a0 = __uint_as_float(us << 16);
    float a1 = __uint_as_float(us & 0xffff0000u);
    float b0 = 0.f, b1 = 0.f, c0 = 0.f, c1 = 0.f;
    float d0 = 0.f, d1 = 0.f, e0 = 0.f, e1 = 0.f;
    float f0 = 0.f, f1 = 0.f, g0 = 0.f, g1 = 0.f;
    float h0 = 0.f, h1 = 0.f, i0 = 0.f, i1 = 0.f;

    int k = 0;
    for (; k + 8 <= dv; k += 8) {
        uint4 q = *(const uint4*)(cv + k);
        int u0 = q.x & 0xffff, u1 = q.x >> 16;
        int u2 = q.y & 0xffff, u3 = q.y >> 16;
        int u4 = q.z & 0xffff, u5 = q.z >> 16;
        int u6 = q.w & 0xffff, u7 = q.w >> 16;
        uint32 w0 = g32[(u0 << 6) + lane];
        uint32 w1 = g32[(u1 << 6) + lane];
        uint32 w2 = g32[(u2 << 6) + lane];
        uint32 w3 = g32[(u3 << 6) + lane];
        uint32 w4 = g32[(u4 << 6) + lane];
        uint32 w5 = g32[(u5 << 6) + lane];
        uint32 w6 = g32[(u6 << 6) + lane];
        uint32 w7 = g32[(u7 << 6) + lane];
        a0 += __uint_as_float(w0 << 16); a1 += __uint_as_float(w0 & 0xffff0000u);
        b0 += __uint_as_float(w1 << 16); b1 += __uint_as_float(w1 & 0xffff0000u);
        c0 += __uint_as_float(w2 << 16); c1 += __uint_as_float(w2 & 0xffff0000u);
        d0 += __uint_as_float(w3 << 16); d1 += __uint_as_float(w3 & 0xffff0000u);
        e0 += __uint_as_float(w4 << 16); e1 += __uint_as_float(w4 & 0xffff0000u);
        f0 += __uint_as_float(w5 << 16); f1 += __uint_as_float(w5 & 0xffff0000u);
        g0 += __uint_as_float(w6 << 16); g1 += __uint_as_float(w6 & 0xffff0000u);
        h0 += __uint_as_float(w7 << 16); h1 += __uint_as_float(w7 & 0xffff0000u);
    }
    for (; k < dv; k++) {
        uint32 w = g32[(cv[k] << 6) + lane];
        i0 += __uint_as_float(w << 16);
        i1 += __uint_as_float(w & 0xffff0000u);
    }
    float di = dis[v];
    float r0 = di * ((((a0 + b0) + (c0 + d0)) + ((e0 + f0) + (g0 + h0))) + i0);
    float r1 = di * ((((a1 + b1) + (c1 + d1)) + ((e1 + f1) + (g1 + h1))) + i1);
    float2 out;
    out.x = r0 > 0.f ? r0 : 0.f;
    out.y = r1 > 0.f ? r1 : 0.f;
    *(float2*)(xout + v * DIM + lane * 2) = out;
}

// ---------------- fused readout: pool (blocks 0-624) + head (625-3124) ----------------

__global__ __launch_bounds__(256) void pool_head(const float* __restrict__ x,
                                                 const int* __restrict__ batch,
                                                 const float* __restrict__ fcw,
                                                 const float* __restrict__ fcb,
                                                 float* __restrict__ xr,
                                                 float* __restrict__ out) {
    if (blockIdx.x < 625) {
        if (threadIdx.x >= 128) return;
        int start = blockIdx.x * 16;
        int t = threadIdx.x;
        int b = batch[start];
        float acc = 0.f;
        for (int n = start; n < start + 16; n++) {
            int bn = batch[n];
            if (bn != b) { atomicAdd(&xr[b * DIM + t], acc); acc = 0.f; b = bn; }
            acc += x[n * DIM + t];
        }
        atomicAdd(&xr[b * DIM + t], acc);
    } else {
        int node = (blockIdx.x - 625) * 4 + (threadIdx.x >> 6);
        int lane = threadIdx.x & 63;
        if (node >= N_NODES) return;
        float xl = x[node * DIM + lane];
        float xh = x[node * DIM + 64 + lane];
        float lg[NCLS];
#pragma unroll
        for (int c = 0; c < NCLS; c++) {
            float p = xl * fcw[lane * NCLS + c] + xh * fcw[(lane + 64) * NCLS + c];
#pragma unroll
            for (int off = 32; off >= 1; off >>= 1) p += __shfl_xor(p, off, 64);
            lg[c] = p + fcb[c];
        }
        float m = lg[0];
#pragma unroll
        for (int c = 1; c < NCLS; c++) m = fmaxf(m, lg[c]);
        float s = 0.f;
#pragma unroll
        for (int c = 0; c < NCLS; c++) s += expf(lg[c] - m);
        float lse = m + logf(s);
        if (lane < NCLS) out[node * NCLS + lane] = lg[lane] - lse;
    }
}

// ---------------- launch ----------------

extern "C" void kernel_launch(void* const* d_in, const int* in_sizes, int n_in,
                              void* d_out, int out_size, void* d_ws, size_t ws_size,
                              hipStream_t stream) {
    const float* x     = (const float*)d_in[0];
    const int*   ei    = (const int*)d_in[1];      // [2, E] int32
    const int*   src   = ei;
    const int*   dst   = ei + N_EDGES;
    const int*   batch = (const int*)d_in[2];
    const float* W[4]  = {(const float*)d_in[3], (const float*)d_in[4],
                          (const float*)d_in[5], (const float*)d_in[6]};
    const float* fcw   = (const float*)d_in[7];
    const float* fcb   = (const float*)d_in[8];

    float* out_ls = (float*)d_out;                 // [N,10]
    float* out_xr = out_ls + N_NODES * NCLS;       // [64,128]

    // workspace layout (16B-aligned)
    int*      deg = (int*)d_ws;                        // 10240 ints
    ushort16* col = (ushort16*)(deg + 10240);          // N*CSTRIDE ushorts (5.12MB)
    float*    dis = (float*)(col + N_NODES * CSTRIDE); // 10240 floats
    ushort16* Gh  = (ushort16*)(dis + 10240);          // N*D bf16
    float*    Xb  = (float*)(Gh + N_NODES * DIM);      // N*D f32

    hipMemsetAsync(deg, 0, 10240 * sizeof(int), stream);
    hipMemsetAsync(out_xr, 0, NGRAPH * DIM * sizeof(float), stream);

    build_gemm1<<<3200, 256, 0, stream>>>(src, dst, deg, col, x, W[0], Gh);
    agg1_kernel<<<N_NODES / 4, 256, 0, stream>>>(Gh, deg, col, dis, Xb);

    for (int l = 1; l < 4; l++) {
        gemm_scale<<<N_NODES / 16, 256, 0, stream>>>(Xb, W[l], dis, Gh);
        agg_kernel<<<N_NODES / 4, 256, 0, stream>>>(Gh, deg, col, dis, Xb);
    }

    pool_head<<<3200, 256, 0, stream>>>(Xb, batch, fcw, fcb, out_xr, out_ls);
}

// Round 7
// 290.384 us; speedup vs baseline: 1.0451x; 1.0451x over previous
//
#include <hip/hip_runtime.h>
#include <math.h>

#define N_NODES 10000
#define N_EDGES 640000
#define DIM     128
#define NCLS    10
#define NGRAPH  64
#define CSTRIDE 128   // padded adjacency stride; deg~Poisson(64), P(deg>=128)~2e-11 (guarded)

typedef unsigned int uint32;
typedef unsigned short ushort16;

__device__ __forceinline__ ushort16 f32_to_bf16_rne(float f) {
    uint32 u = __float_as_uint(f);
    u = (u + 0x7fffu + ((u >> 16) & 1u)) >> 16;   // round-to-nearest-even
    return (ushort16)u;
}

// ---------------- fused adjacency build + layer-1 GEMM ----------------
// Blocks 0..624: g1 = bf16(x @ W1) (unscaled; needs no deg, runs concurrent
// with build). Blocks 625..3124: scatter edges into padded ushort adjacency.
// CSTRIDE=128 keeps col at 2.56 MB so touched lines fit per-XCD L2 (testing
// the dirty-line-capacity hypothesis for R5/R6's 34 MB write amplification).
__global__ __launch_bounds__(256) void build_gemm1(const int* __restrict__ src,
                                                   const int* __restrict__ dst,
                                                   int* __restrict__ deg,
                                                   ushort16* __restrict__ col,
                                                   const float* __restrict__ X,
                                                   const float* __restrict__ W,
                                                   ushort16* __restrict__ Gh) {
    if (blockIdx.x < 625) {
        int c    = threadIdx.x & 127;
        int rg   = threadIdx.x >> 7;
        int row0 = blockIdx.x * 16 + rg * 8;
        const float* xb = X + row0 * DIM;
        float acc[8] = {0.f, 0.f, 0.f, 0.f, 0.f, 0.f, 0.f, 0.f};
        for (int k = 0; k < DIM; k += 4) {
            float w0 = W[(k + 0) * DIM + c];
            float w1 = W[(k + 1) * DIM + c];
            float w2 = W[(k + 2) * DIM + c];
            float w3 = W[(k + 3) * DIM + c];
#pragma unroll
            for (int r = 0; r < 8; r++) {
                float4 xv = *(const float4*)(xb + r * DIM + k);
                acc[r] += xv.x * w0 + xv.y * w1 + xv.z * w2 + xv.w * w3;
            }
        }
#pragma unroll
        for (int r = 0; r < 8; r++)
            Gh[(row0 + r) * DIM + c] = f32_to_bf16_rne(acc[r]);
    } else {
        int e = (blockIdx.x - 625) * 256 + threadIdx.x;
        if (e < N_EDGES) {
            int s = src[e];
            int d = dst[e];
            int r = atomicAdd(&deg[d], 1);
            if (r < CSTRIDE) col[(d << 7) + r] = (ushort16)s;
        }
    }
}

// ---------------- layer-1 aggregation (applies per-src scaling on the fly) ----------------
// out[v] = relu( sv * ( sv*g[v] + sum_u s_u*g[u] ) ), s = rsqrt(deg+1).
// Also writes dis[v]=sv for later layers. One wave per node, lane owns 2 feats.
__global__ __launch_bounds__(256) void agg1_kernel(const ushort16* __restrict__ Gh,
                                                   const int* __restrict__ deg,
                                                   const ushort16* __restrict__ col,
                                                   float* __restrict__ dis,
                                                   float* __restrict__ xout) {
    int v    = blockIdx.x * 4 + (threadIdx.x >> 6);
    int lane = threadIdx.x & 63;
    const uint32* g32 = (const uint32*)Gh;
    const ushort16* cv = col + (v << 7);
    int dv = deg[v];
    float sv = rsqrtf((float)dv + 1.0f);
    if (lane == 0) dis[v] = sv;

    uint32 us = g32[(v << 6) + lane];
    float a0 = sv * __uint_as_float(us << 16);
    float a1 = sv * __uint_as_float(us & 0xffff0000u);
    float b0 = 0.f, b1 = 0.f, c0 = 0.f, c1 = 0.f;
    float d0 = 0.f, d1 = 0.f, e0 = 0.f, e1 = 0.f;

    int k = 0;
    for (; k + 8 <= dv; k += 8) {
        uint4 q = *(const uint4*)(cv + k);
        int u0 = q.x & 0xffff, u1 = q.x >> 16;
        int u2 = q.y & 0xffff, u3 = q.y >> 16;
        int u4 = q.z & 0xffff, u5 = q.z >> 16;
        int u6 = q.w & 0xffff, u7 = q.w >> 16;
        uint32 w0 = g32[(u0 << 6) + lane];
        uint32 w1 = g32[(u1 << 6) + lane];
        uint32 w2 = g32[(u2 << 6) + lane];
        uint32 w3 = g32[(u3 << 6) + lane];
        uint32 w4 = g32[(u4 << 6) + lane];
        uint32 w5 = g32[(u5 << 6) + lane];
        uint32 w6 = g32[(u6 << 6) + lane];
        uint32 w7 = g32[(u7 << 6) + lane];
        float s0 = rsqrtf((float)deg[u0] + 1.0f);
        float s1 = rsqrtf((float)deg[u1] + 1.0f);
        float s2 = rsqrtf((float)deg[u2] + 1.0f);
        float s3 = rsqrtf((float)deg[u3] + 1.0f);
        float s4 = rsqrtf((float)deg[u4] + 1.0f);
        float s5 = rsqrtf((float)deg[u5] + 1.0f);
        float s6 = rsqrtf((float)deg[u6] + 1.0f);
        float s7 = rsqrtf((float)deg[u7] + 1.0f);
        a0 += s0 * __uint_as_float(w0 << 16); a1 += s0 * __uint_as_float(w0 & 0xffff0000u);
        b0 += s1 * __uint_as_float(w1 << 16); b1 += s1 * __uint_as_float(w1 & 0xffff0000u);
        c0 += s2 * __uint_as_float(w2 << 16); c1 += s2 * __uint_as_float(w2 & 0xffff0000u);
        d0 += s3 * __uint_as_float(w3 << 16); d1 += s3 * __uint_as_float(w3 & 0xffff0000u);
        a0 += s4 * __uint_as_float(w4 << 16); a1 += s4 * __uint_as_float(w4 & 0xffff0000u);
        b0 += s5 * __uint_as_float(w5 << 16); b1 += s5 * __uint_as_float(w5 & 0xffff0000u);
        c0 += s6 * __uint_as_float(w6 << 16); c1 += s6 * __uint_as_float(w6 & 0xffff0000u);
        d0 += s7 * __uint_as_float(w7 << 16); d1 += s7 * __uint_as_float(w7 & 0xffff0000u);
    }
    for (; k < dv; k++) {
        int u = cv[k];
        uint32 w = g32[(u << 6) + lane];
        float s = rsqrtf((float)deg[u] + 1.0f);
        e0 += s * __uint_as_float(w << 16);
        e1 += s * __uint_as_float(w & 0xffff0000u);
    }
    float r0 = sv * (((a0 + b0) + (c0 + d0)) + e0);
    float r1 = sv * (((a1 + b1) + (c1 + d1)) + e1);
    float2 out;
    out.x = r0 > 0.f ? r0 : 0.f;
    out.y = r1 > 0.f ? r1 : 0.f;
    *(float2*)(xout + v * DIM + lane * 2) = out;
}

// ---------------- layers 2-4 ----------------

// g = bf16( (x @ W) * dis[row] )
__global__ __launch_bounds__(256) void gemm_scale(const float* __restrict__ X,
                                                  const float* __restrict__ W,
                                                  const float* __restrict__ dis,
                                                  ushort16* __restrict__ Gh) {
    int c    = threadIdx.x & 127;
    int rg   = threadIdx.x >> 7;
    int row0 = blockIdx.x * 16 + rg * 8;
    const float* xb = X + row0 * DIM;
    float acc[8] = {0.f, 0.f, 0.f, 0.f, 0.f, 0.f, 0.f, 0.f};
    for (int k = 0; k < DIM; k += 4) {
        float w0 = W[(k + 0) * DIM + c];
        float w1 = W[(k + 1) * DIM + c];
        float w2 = W[(k + 2) * DIM + c];
        float w3 = W[(k + 3) * DIM + c];
#pragma unroll
        for (int r = 0; r < 8; r++) {
            float4 xv = *(const float4*)(xb + r * DIM + k);
            acc[r] += xv.x * w0 + xv.y * w1 + xv.z * w2 + xv.w * w3;
        }
    }
#pragma unroll
    for (int r = 0; r < 8; r++) {
        int row = row0 + r;
        Gh[row * DIM + c] = f32_to_bf16_rne(acc[r] * dis[row]);
    }
}

// x_out[v] = relu( dis[v] * ( g[v] + sum_u g[u] ) )   (g already dis-scaled)
__global__ __launch_bounds__(256) void agg_kernel(const ushort16* __restrict__ Gh,
                                                  const int* __restrict__ deg,
                                                  const ushort16* __restrict__ col,
                                                  const float* __restrict__ dis,
                                                  float* __restrict__ xout) {
    int v    = blockIdx.x * 4 + (threadIdx.x >> 6);
    int lane = threadIdx.x & 63;
    const uint32* g32 = (const uint32*)Gh;
    const ushort16* cv = col + (v << 7);
    int dv = deg[v];

    uint32 us = g32[(v << 6) + lane];
    float a0 = __uint_as_float(us << 16);
    float a1 = __uint_as_float(us & 0xffff0000u);
    float b0 = 0.f, b1 = 0.f, c0 = 0.f, c1 = 0.f;
    float d0 = 0.f, d1 = 0.f, e0 = 0.f, e1 = 0.f;
    float f0 = 0.f, f1 = 0.f, g0 = 0.f, g1 = 0.f;
    float h0 = 0.f, h1 = 0.f, i0 = 0.f, i1 = 0.f;

    int k = 0;
    for (; k + 8 <= dv; k += 8) {
        uint4 q = *(const uint4*)(cv + k);
        int u0 = q.x & 0xffff, u1 = q.x >> 16;
        int u2 = q.y & 0xffff, u3 = q.y >> 16;
        int u4 = q.z & 0xffff, u5 = q.z >> 16;
        int u6 = q.w & 0xffff, u7 = q.w >> 16;
        uint32 w0 = g32[(u0 << 6) + lane];
        uint32 w1 = g32[(u1 << 6) + lane];
        uint32 w2 = g32[(u2 << 6) + lane];
        uint32 w3 = g32[(u3 << 6) + lane];
        uint32 w4 = g32[(u4 << 6) + lane];
        uint32 w5 = g32[(u5 << 6) + lane];
        uint32 w6 = g32[(u6 << 6) + lane];
        uint32 w7 = g32[(u7 << 6) + lane];
        a0 += __uint_as_float(w0 << 16); a1 += __uint_as_float(w0 & 0xffff0000u);
        b0 += __uint_as_float(w1 << 16); b1 += __uint_as_float(w1 & 0xffff0000u);
        c0 += __uint_as_float(w2 << 16); c1 += __uint_as_float(w2 & 0xffff0000u);
        d0 += __uint_as_float(w3 << 16); d1 += __uint_as_float(w3 & 0xffff0000u);
        e0 += __uint_as_float(w4 << 16); e1 += __uint_as_float(w4 & 0xffff0000u);
        f0 += __uint_as_float(w5 << 16); f1 += __uint_as_float(w5 & 0xffff0000u);
        g0 += __uint_as_float(w6 << 16); g1 += __uint_as_float(w6 & 0xffff0000u);
        h0 += __uint_as_float(w7 << 16); h1 += __uint_as_float(w7 & 0xffff0000u);
    }
    for (; k < dv; k++) {
        uint32 w = g32[(cv[k] << 6) + lane];
        i0 += __uint_as_float(w << 16);
        i1 += __uint_as_float(w & 0xffff0000u);
    }
    float di = dis[v];
    float r0 = di * ((((a0 + b0) + (c0 + d0)) + ((e0 + f0) + (g0 + h0))) + i0);
    float r1 = di * ((((a1 + b1) + (c1 + d1)) + ((e1 + f1) + (g1 + h1))) + i1);
    float2 out;
    out.x = r0 > 0.f ? r0 : 0.f;
    out.y = r1 > 0.f ? r1 : 0.f;
    *(float2*)(xout + v * DIM + lane * 2) = out;
}

// ---------------- fused readout: pool (blocks 0-624) + head (625-3124) ----------------

__global__ __launch_bounds__(256) void pool_head(const float* __restrict__ x,
                                                 const int* __restrict__ batch,
                                                 const float* __restrict__ fcw,
                                                 const float* __restrict__ fcb,
                                                 float* __restrict__ xr,
                                                 float* __restrict__ out) {
    if (blockIdx.x < 625) {
        if (threadIdx.x >= 128) return;
        int start = blockIdx.x * 16;
        int t = threadIdx.x;
        int b = batch[start];
        float acc = 0.f;
        for (int n = start; n < start + 16; n++) {
            int bn = batch[n];
            if (bn != b) { atomicAdd(&xr[b * DIM + t], acc); acc = 0.f; b = bn; }
            acc += x[n * DIM + t];
        }
        atomicAdd(&xr[b * DIM + t], acc);
    } else {
        int node = (blockIdx.x - 625) * 4 + (threadIdx.x >> 6);
        int lane = threadIdx.x & 63;
        if (node >= N_NODES) return;
        float xl = x[node * DIM + lane];
        float xh = x[node * DIM + 64 + lane];
        float lg[NCLS];
#pragma unroll
        for (int c = 0; c < NCLS; c++) {
            float p = xl * fcw[lane * NCLS + c] + xh * fcw[(lane + 64) * NCLS + c];
#pragma unroll
            for (int off = 32; off >= 1; off >>= 1) p += __shfl_xor(p, off, 64);
            lg[c] = p + fcb[c];
        }
        float m = lg[0];
#pragma unroll
        for (int c = 1; c < NCLS; c++) m = fmaxf(m, lg[c]);
        float s = 0.f;
#pragma unroll
        for (int c = 0; c < NCLS; c++) s += expf(lg[c] - m);
        float lse = m + logf(s);
        if (lane < NCLS) out[node * NCLS + lane] = lg[lane] - lse;
    }
}

// ---------------- launch ----------------

extern "C" void kernel_launch(void* const* d_in, const int* in_sizes, int n_in,
                              void* d_out, int out_size, void* d_ws, size_t ws_size,
                              hipStream_t stream) {
    const float* x     = (const float*)d_in[0];
    const int*   ei    = (const int*)d_in[1];      // [2, E] int32
    const int*   src   = ei;
    const int*   dst   = ei + N_EDGES;
    const int*   batch = (const int*)d_in[2];
    const float* W[4]  = {(const float*)d_in[3], (const float*)d_in[4],
                          (const float*)d_in[5], (const float*)d_in[6]};
    const float* fcw   = (const float*)d_in[7];
    const float* fcb   = (const float*)d_in[8];

    float* out_ls = (float*)d_out;                 // [N,10]
    float* out_xr = out_ls + N_NODES * NCLS;       // [64,128]

    // workspace layout (16B-aligned)
    int*      deg = (int*)d_ws;                        // 10240 ints
    ushort16* col = (ushort16*)(deg + 10240);          // N*CSTRIDE ushorts (2.56MB)
    float*    dis = (float*)(col + N_NODES * CSTRIDE); // 10240 floats
    ushort16* Gh  = (ushort16*)(dis + 10240);          // N*D bf16
    float*    Xb  = (float*)(Gh + N_NODES * DIM);      // N*D f32

    hipMemsetAsync(deg, 0, 10240 * sizeof(int), stream);
    hipMemsetAsync(out_xr, 0, NGRAPH * DIM * sizeof(float), stream);

    build_gemm1<<<3125, 256, 0, stream>>>(src, dst, deg, col, x, W[0], Gh);
    agg1_kernel<<<N_NODES / 4, 256, 0, stream>>>(Gh, deg, col, dis, Xb);

    for (int l = 1; l < 4; l++) {
        gemm_scale<<<N_NODES / 16, 256, 0, stream>>>(Xb, W[l], dis, Gh);
        agg_kernel<<<N_NODES / 4, 256, 0, stream>>>(Gh, deg, col, dis, Xb);
    }

    pool_head<<<3125, 256, 0, stream>>>(Xb, batch, fcw, fcb, out_xr, out_ls);
}

// Round 8
// 277.276 us; speedup vs baseline: 1.0945x; 1.0473x over previous
//
#include <hip/hip_runtime.h>
#include <math.h>

#define N_NODES 10000
#define N_EDGES 640000
#define DIM     128
#define NCLS    10
#define NGRAPH  64
#define NB      157    // buckets of 64 nodes (dst>>6)
#define BCAP    4608   // bucket capacity; bucket ~Poisson(4076), 8 sigma pad
#define EPB     4000   // edges per bin-block (160 blocks)

typedef unsigned int uint32;
typedef unsigned short ushort16;

__device__ __forceinline__ ushort16 f32_to_bf16_rne(float f) {
    uint32 u = __float_as_uint(f);
    u = (u + 0x7fffu + ((u >> 16) & 1u)) >> 16;   // round-to-nearest-even
    return (ushort16)u;
}

// ---------------- pass A: edge binning (+ fused layer-1 GEMM) ----------------
// Blocks 0..624: g1 = bf16(x @ W1) (unscaled; no dependence on deg).
// Blocks 625..784: bin 4000 edges each into NB bucket regions. All global
// writes are contiguous runs (LDS-relocated first); one global atomic per
// (block,bucket). Kills R5-R7's 34 MB partial-line write amplification.
__global__ __launch_bounds__(256) void binA_gemm1(const int* __restrict__ src,
                                                  const int* __restrict__ dst,
                                                  int* __restrict__ gcursor,
                                                  uint32* __restrict__ bins,
                                                  const float* __restrict__ X,
                                                  const float* __restrict__ W,
                                                  ushort16* __restrict__ Gh) {
    __shared__ uint32 pk[EPB];
    __shared__ int cntS[NB], offS[NB], curS[NB], gposS[NB];

    if (blockIdx.x < 625) {
        int c    = threadIdx.x & 127;
        int rg   = threadIdx.x >> 7;
        int row0 = blockIdx.x * 16 + rg * 8;
        const float* xb = X + row0 * DIM;
        float acc[8] = {0.f, 0.f, 0.f, 0.f, 0.f, 0.f, 0.f, 0.f};
        for (int k = 0; k < DIM; k += 4) {
            float w0 = W[(k + 0) * DIM + c];
            float w1 = W[(k + 1) * DIM + c];
            float w2 = W[(k + 2) * DIM + c];
            float w3 = W[(k + 3) * DIM + c];
#pragma unroll
            for (int r = 0; r < 8; r++) {
                float4 xv = *(const float4*)(xb + r * DIM + k);
                acc[r] += xv.x * w0 + xv.y * w1 + xv.z * w2 + xv.w * w3;
            }
        }
#pragma unroll
        for (int r = 0; r < 8; r++)
            Gh[(row0 + r) * DIM + c] = f32_to_bf16_rne(acc[r]);
        return;
    }

    int ab  = blockIdx.x - 625;     // 0..159
    int tid = threadIdx.x;
    for (int i = tid; i < NB; i += 256) cntS[i] = 0;
    __syncthreads();

    int base = ab * EPB;
    uint32 pr[16];
#pragma unroll
    for (int it = 0; it < 16; it++) {
        int i = it * 256 + tid;
        uint32 p = 0xffffffffu;
        if (i < EPB) {
            int e = base + i;
            p = ((uint32)dst[e] << 16) | (uint32)src[e];
            atomicAdd(&cntS[p >> 22], 1);     // p>>22 == dst>>6
        }
        pr[it] = p;
    }
    __syncthreads();

    // exclusive scan of cntS by wave 0 (3 rounds of 64)
    if (tid < 64) {
        int carry = 0;
        for (int r = 0; r < 3; r++) {
            int idx = r * 64 + tid;
            int v = (idx < NB) ? cntS[idx] : 0;
            int inc = v;
#pragma unroll
            for (int o = 1; o < 64; o <<= 1) {
                int u = __shfl_up(inc, o, 64);
                if (tid >= o) inc += u;
            }
            if (idx < NB) { offS[idx] = inc - v + carry; curS[idx] = inc - v + carry; }
            carry += __shfl(inc, 63, 64);
        }
    }
    __syncthreads();

    // relocate into LDS so global writes are sequential runs
#pragma unroll
    for (int it = 0; it < 16; it++) {
        uint32 p = pr[it];
        if (p != 0xffffffffu) {
            int b = p >> 22;
            pk[atomicAdd(&curS[b], 1)] = p;
        }
    }
    __syncthreads();

    if (tid < NB) gposS[tid] = atomicAdd(&gcursor[tid], cntS[tid]);
    __syncthreads();

#pragma unroll
    for (int it = 0; it < 16; it++) {
        int i = it * 256 + tid;
        if (i < EPB) {
            uint32 u = pk[i];
            int b = u >> 22;
            int gp = gposS[b] + (i - offS[b]);
            if (gp < BCAP) bins[b * BCAP + gp] = u;
        }
    }
}

// ---------------- pass B: bucket -> padded adjacency via LDS tile ----------------
// One block per bucket (64 nodes). Coalesced read of the bucket run, LDS-atomic
// scatter into a 16 KB tile, contiguous uint4 write-out. Also emits deg & dis.
__global__ __launch_bounds__(256) void binB(const int* __restrict__ gcursor,
                                            const uint32* __restrict__ bins,
                                            ushort16* __restrict__ col,
                                            int* __restrict__ deg,
                                            float* __restrict__ dis) {
    __shared__ ushort16 adj[64 * 128];   // 16 KB
    __shared__ int cnt2[64];
    int b   = blockIdx.x;
    int tid = threadIdx.x;
    if (tid < 64) cnt2[tid] = 0;
    __syncthreads();
    int tc = gcursor[b];
    if (tc > BCAP) tc = BCAP;
    const uint32* bb = bins + b * BCAP;
    for (int i = tid; i < tc; i += 256) {
        uint32 u = bb[i];
        int local = (u >> 16) & 63;
        int r = atomicAdd(&cnt2[local], 1);
        if (r < 128) adj[(local << 7) + r] = (ushort16)(u & 0xffffu);
    }
    __syncthreads();
    uint4* dstp = (uint4*)(col + (size_t)b * 64 * 128);
    const uint4* srcp = (const uint4*)adj;
    for (int j = tid; j < 1024; j += 256) dstp[j] = srcp[j];
    if (tid < 64) {
        int node = b * 64 + tid;          // arrays padded to 10240
        int c = cnt2[tid] < 128 ? cnt2[tid] : 128;
        deg[node] = c;
        dis[node] = rsqrtf((float)c + 1.0f);
    }
}

// ---------------- layer-1 aggregation (per-src dis gathered, precomputed) ----------------
__global__ __launch_bounds__(256) void agg1_kernel(const ushort16* __restrict__ Gh,
                                                   const int* __restrict__ deg,
                                                   const ushort16* __restrict__ col,
                                                   const float* __restrict__ dis,
                                                   float* __restrict__ xout) {
    int v    = blockIdx.x * 4 + (threadIdx.x >> 6);
    int lane = threadIdx.x & 63;
    const uint32* g32 = (const uint32*)Gh;
    const ushort16* cv = col + (v << 7);
    int dv = deg[v];
    float sv = dis[v];

    uint32 us = g32[(v << 6) + lane];
    float a0 = sv * __uint_as_float(us << 16);
    float a1 = sv * __uint_as_float(us & 0xffff0000u);
    float b0 = 0.f, b1 = 0.f, c0 = 0.f, c1 = 0.f;
    float d0 = 0.f, d1 = 0.f, e0 = 0.f, e1 = 0.f;

    int k = 0;
    for (; k + 8 <= dv; k += 8) {
        uint4 q = *(const uint4*)(cv + k);
        int u0 = q.x & 0xffff, u1 = q.x >> 16;
        int u2 = q.y & 0xffff, u3 = q.y >> 16;
        int u4 = q.z & 0xffff, u5 = q.z >> 16;
        int u6 = q.w & 0xffff, u7 = q.w >> 16;
        uint32 w0 = g32[(u0 << 6) + lane];
        uint32 w1 = g32[(u1 << 6) + lane];
        uint32 w2 = g32[(u2 << 6) + lane];
        uint32 w3 = g32[(u3 << 6) + lane];
        uint32 w4 = g32[(u4 << 6) + lane];
        uint32 w5 = g32[(u5 << 6) + lane];
        uint32 w6 = g32[(u6 << 6) + lane];
        uint32 w7 = g32[(u7 << 6) + lane];
        float s0 = dis[u0], s1 = dis[u1], s2 = dis[u2], s3 = dis[u3];
        float s4 = dis[u4], s5 = dis[u5], s6 = dis[u6], s7 = dis[u7];
        a0 += s0 * __uint_as_float(w0 << 16); a1 += s0 * __uint_as_float(w0 & 0xffff0000u);
        b0 += s1 * __uint_as_float(w1 << 16); b1 += s1 * __uint_as_float(w1 & 0xffff0000u);
        c0 += s2 * __uint_as_float(w2 << 16); c1 += s2 * __uint_as_float(w2 & 0xffff0000u);
        d0 += s3 * __uint_as_float(w3 << 16); d1 += s3 * __uint_as_float(w3 & 0xffff0000u);
        a0 += s4 * __uint_as_float(w4 << 16); a1 += s4 * __uint_as_float(w4 & 0xffff0000u);
        b0 += s5 * __uint_as_float(w5 << 16); b1 += s5 * __uint_as_float(w5 & 0xffff0000u);
        c0 += s6 * __uint_as_float(w6 << 16); c1 += s6 * __uint_as_float(w6 & 0xffff0000u);
        d0 += s7 * __uint_as_float(w7 << 16); d1 += s7 * __uint_as_float(w7 & 0xffff0000u);
    }
    for (; k < dv; k++) {
        int u = cv[k];
        uint32 w = g32[(u << 6) + lane];
        float s = dis[u];
        e0 += s * __uint_as_float(w << 16);
        e1 += s * __uint_as_float(w & 0xffff0000u);
    }
    float r0 = sv * (((a0 + b0) + (c0 + d0)) + e0);
    float r1 = sv * (((a1 + b1) + (c1 + d1)) + e1);
    float2 out;
    out.x = r0 > 0.f ? r0 : 0.f;
    out.y = r1 > 0.f ? r1 : 0.f;
    *(float2*)(xout + v * DIM + lane * 2) = out;
}

// ---------------- layers 2-4 ----------------

__global__ __launch_bounds__(256) void gemm_scale(const float* __restrict__ X,
                                                  const float* __restrict__ W,
                                                  const float* __restrict__ dis,
                                                  ushort16* __restrict__ Gh) {
    int c    = threadIdx.x & 127;
    int rg   = threadIdx.x >> 7;
    int row0 = blockIdx.x * 16 + rg * 8;
    const float* xb = X + row0 * DIM;
    float acc[8] = {0.f, 0.f, 0.f, 0.f, 0.f, 0.f, 0.f, 0.f};
    for (int k = 0; k < DIM; k += 4) {
        float w0 = W[(k + 0) * DIM + c];
        float w1 = W[(k + 1) * DIM + c];
        float w2 = W[(k + 2) * DIM + c];
        float w3 = W[(k + 3) * DIM + c];
#pragma unroll
        for (int r = 0; r < 8; r++) {
            float4 xv = *(const float4*)(xb + r * DIM + k);
            acc[r] += xv.x * w0 + xv.y * w1 + xv.z * w2 + xv.w * w3;
        }
    }
#pragma unroll
    for (int r = 0; r < 8; r++) {
        int row = row0 + r;
        Gh[row * DIM + c] = f32_to_bf16_rne(acc[r] * dis[row]);
    }
}

__global__ __launch_bounds__(256) void agg_kernel(const ushort16* __restrict__ Gh,
                                                  const int* __restrict__ deg,
                                                  const ushort16* __restrict__ col,
                                                  const float* __restrict__ dis,
                                                  float* __restrict__ xout) {
    int v    = blockIdx.x * 4 + (threadIdx.x >> 6);
    int lane = threadIdx.x & 63;
    const uint32* g32 = (const uint32*)Gh;
    const ushort16* cv = col + (v << 7);
    int dv = deg[v];

    uint32 us = g32[(v << 6) + lane];
    float a0 = __uint_as_float(us << 16);
    float a1 = __uint_as_float(us & 0xffff0000u);
    float b0 = 0.f, b1 = 0.f, c0 = 0.f, c1 = 0.f;
    float d0 = 0.f, d1 = 0.f, e0 = 0.f, e1 = 0.f;
    float f0 = 0.f, f1 = 0.f, g0 = 0.f, g1 = 0.f;
    float h0 = 0.f, h1 = 0.f, i0 = 0.f, i1 = 0.f;

    int k = 0;
    for (; k + 8 <= dv; k += 8) {
        uint4 q = *(const uint4*)(cv + k);
        int u0 = q.x & 0xffff, u1 = q.x >> 16;
        int u2 = q.y & 0xffff, u3 = q.y >> 16;
        int u4 = q.z & 0xffff, u5 = q.z >> 16;
        int u6 = q.w & 0xffff, u7 = q.w >> 16;
        uint32 w0 = g32[(u0 << 6) + lane];
        uint32 w1 = g32[(u1 << 6) + lane];
        uint32 w2 = g32[(u2 << 6) + lane];
        uint32 w3 = g32[(u3 << 6) + lane];
        uint32 w4 = g32[(u4 << 6) + lane];
        uint32 w5 = g32[(u5 << 6) + lane];
        uint32 w6 = g32[(u6 << 6) + lane];
        uint32 w7 = g32[(u7 << 6) + lane];
        a0 += __uint_as_float(w0 << 16); a1 += __uint_as_float(w0 & 0xffff0000u);
        b0 += __uint_as_float(w1 << 16); b1 += __uint_as_float(w1 & 0xffff0000u);
        c0 += __uint_as_float(w2 << 16); c1 += __uint_as_float(w2 & 0xffff0000u);
        d0 += __uint_as_float(w3 << 16); d1 += __uint_as_float(w3 & 0xffff0000u);
        e0 += __uint_as_float(w4 << 16); e1 += __uint_as_float(w4 & 0xffff0000u);
        f0 += __uint_as_float(w5 << 16); f1 += __uint_as_float(w5 & 0xffff0000u);
        g0 += __uint_as_float(w6 << 16); g1 += __uint_as_float(w6 & 0xffff0000u);
        h0 += __uint_as_float(w7 << 16); h1 += __uint_as_float(w7 & 0xffff0000u);
    }
    for (; k < dv; k++) {
        uint32 w = g32[(cv[k] << 6) + lane];
        i0 += __uint_as_float(w << 16);
        i1 += __uint_as_float(w & 0xffff0000u);
    }
    float di = dis[v];
    float r0 = di * ((((a0 + b0) + (c0 + d0)) + ((e0 + f0) + (g0 + h0))) + i0);
    float r1 = di * ((((a1 + b1) + (c1 + d1)) + ((e1 + f1) + (g1 + h1))) + i1);
    float2 out;
    out.x = r0 > 0.f ? r0 : 0.f;
    out.y = r1 > 0.f ? r1 : 0.f;
    *(float2*)(xout + v * DIM + lane * 2) = out;
}

// ---------------- fused readout: pool (blocks 0-624) + head (625-3124) ----------------

__global__ __launch_bounds__(256) void pool_head(const float* __restrict__ x,
                                                 const int* __restrict__ batch,
                                                 const float* __restrict__ fcw,
                                                 const float* __restrict__ fcb,
                                                 float* __restrict__ xr,
                                                 float* __restrict__ out) {
    if (blockIdx.x < 625) {
        if (threadIdx.x >= 128) return;
        int start = blockIdx.x * 16;
        int t = threadIdx.x;
        int b = batch[start];
        float acc = 0.f;
        for (int n = start; n < start + 16; n++) {
            int bn = batch[n];
            if (bn != b) { atomicAdd(&xr[b * DIM + t], acc); acc = 0.f; b = bn; }
            acc += x[n * DIM + t];
        }
        atomicAdd(&xr[b * DIM + t], acc);
    } else {
        int node = (blockIdx.x - 625) * 4 + (threadIdx.x >> 6);
        int lane = threadIdx.x & 63;
        if (node >= N_NODES) return;
        float xl = x[node * DIM + lane];
        float xh = x[node * DIM + 64 + lane];
        float lg[NCLS];
#pragma unroll
        for (int c = 0; c < NCLS; c++) {
            float p = xl * fcw[lane * NCLS + c] + xh * fcw[(lane + 64) * NCLS + c];
#pragma unroll
            for (int off = 32; off >= 1; off >>= 1) p += __shfl_xor(p, off, 64);
            lg[c] = p + fcb[c];
        }
        float m = lg[0];
#pragma unroll
        for (int c = 1; c < NCLS; c++) m = fmaxf(m, lg[c]);
        float s = 0.f;
#pragma unroll
        for (int c = 0; c < NCLS; c++) s += expf(lg[c] - m);
        float lse = m + logf(s);
        if (lane < NCLS) out[node * NCLS + lane] = lg[lane] - lse;
    }
}

// ---------------- launch ----------------

extern "C" void kernel_launch(void* const* d_in, const int* in_sizes, int n_in,
                              void* d_out, int out_size, void* d_ws, size_t ws_size,
                              hipStream_t stream) {
    const float* x     = (const float*)d_in[0];
    const int*   ei    = (const int*)d_in[1];      // [2, E] int32
    const int*   src   = ei;
    const int*   dst   = ei + N_EDGES;
    const int*   batch = (const int*)d_in[2];
    const float* W[4]  = {(const float*)d_in[3], (const float*)d_in[4],
                          (const float*)d_in[5], (const float*)d_in[6]};
    const float* fcw   = (const float*)d_in[7];
    const float* fcb   = (const float*)d_in[8];

    float* out_ls = (float*)d_out;                 // [N,10]
    float* out_xr = out_ls + N_NODES * NCLS;       // [64,128]

    // workspace layout (16B-aligned element offsets)
    int*      gcursor = (int*)d_ws;                       // 256 ints
    int*      deg     = gcursor + 256;                    // 10240 ints
    float*    dis     = (float*)(deg + 10240);            // 10240 floats
    uint32*   bins    = (uint32*)(dis + 10240);           // NB*BCAP uint32 (2.89MB)
    ushort16* col     = (ushort16*)(bins + NB * BCAP);    // NB*64*128 ushorts (2.57MB)
    ushort16* Gh      = col + (size_t)NB * 64 * 128;      // N*D bf16
    float*    Xb      = (float*)(Gh + (size_t)N_NODES * DIM); // N*D f32

    hipMemsetAsync(gcursor, 0, 256 * sizeof(int), stream);
    hipMemsetAsync(out_xr, 0, NGRAPH * DIM * sizeof(float), stream);

    binA_gemm1<<<785, 256, 0, stream>>>(src, dst, gcursor, bins, x, W[0], Gh);
    binB      <<<NB, 256, 0, stream>>>(gcursor, bins, col, deg, dis);
    agg1_kernel<<<N_NODES / 4, 256, 0, stream>>>(Gh, deg, col, dis, Xb);

    for (int l = 1; l < 4; l++) {
        gemm_scale<<<N_NODES / 16, 256, 0, stream>>>(Xb, W[l], dis, Gh);
        agg_kernel<<<N_NODES / 4, 256, 0, stream>>>(Gh, deg, col, dis, Xb);
    }

    pool_head<<<3125, 256, 0, stream>>>(Xb, batch, fcw, fcb, out_xr, out_ls);
}